// Round 4
// baseline (369.720 us; speedup 1.0000x reference)
//
#include <hip/hip_runtime.h>

// Problem constants (B, LQ, LK, D from the reference)
#define B_  8
#define LQ_ 2048
#define LK_ 2048
#define D_  1024

typedef unsigned short u16;
using short8  = __attribute__((ext_vector_type(8))) short;   // 8 bf16 = 4 VGPRs (MFMA A/B frag)
using floatx4 = __attribute__((ext_vector_type(4))) float;   // MFMA C/D frag

#define GAS __attribute__((address_space(1)))
#define LAS __attribute__((address_space(3)))

__device__ __forceinline__ u16 f2bf(float f) {
  unsigned u = __float_as_uint(f);
  u += 0x7fffu + ((u >> 16) & 1u);   // round-to-nearest-even
  return (u16)(u >> 16);
}
__device__ __forceinline__ float bf2f(u16 h) {
  return __uint_as_float(((unsigned)h) << 16);
}

// ---------------------------------------------------------------------------
// prep (unchanged)
// ---------------------------------------------------------------------------
__global__ void prep(const float* __restrict__ in, const float* __restrict__ mem,
                     const float* __restrict__ ds, u16* __restrict__ qb,
                     u16* __restrict__ mb, u16* __restrict__ mbT,
                     float* __restrict__ denom) {
  __shared__ u16 tile[64][68];
  int tid = threadIdx.x;
  int tx = tid & 15, ty = tid >> 4;
  int b = blockIdx.z;

  if (denom && blockIdx.y == 16 && blockIdx.x == 0 && blockIdx.z == 0) {
    float4 z = {0.f, 0.f, 0.f, 0.f};
    float4* d4 = (float4*)denom;
#pragma unroll
    for (int i = 0; i < (B_ * LQ_ / 4) / 256; i++)
      d4[tid + i * 256] = z;
  }

  if (blockIdx.y < 16) {
    int k0 = blockIdx.x * 64, d0 = blockIdx.y * 64;
    const float* mB = mem + (size_t)b * LK_ * D_;
    u16* mbB = mb  + (size_t)b * LK_ * D_;
    u16* mtB = mbT + (size_t)b * D_ * LK_;
#pragma unroll
    for (int i = 0; i < 4; i++) {
      int r = ty + 16 * i;
      float4 v = *(const float4*)(mB + (size_t)(k0 + r) * D_ + d0 + tx * 4);
      ushort4 h;
      h.x = f2bf(v.x); h.y = f2bf(v.y); h.z = f2bf(v.z); h.w = f2bf(v.w);
      *(ushort4*)(mbB + (size_t)(k0 + r) * D_ + d0 + tx * 4) = h;
      *(ushort4*)(&tile[r][tx * 4]) = h;
    }
    __syncthreads();
#pragma unroll
    for (int i = 0; i < 4; i++) {
      int rr = ty + 16 * i;
      ushort4 o;
      o.x = tile[tx * 4 + 0][rr];
      o.y = tile[tx * 4 + 1][rr];
      o.z = tile[tx * 4 + 2][rr];
      o.w = tile[tx * 4 + 3][rr];
      *(ushort4*)(mtB + (size_t)(d0 + rr) * LK_ + k0 + tx * 4) = o;
    }
  } else {
    int q0 = blockIdx.x * 64, d0 = (blockIdx.y - 16) * 64;
    const float* iB = in + (size_t)b * LQ_ * D_;
    u16* qB = qb + (size_t)b * LQ_ * D_;
    float4 s4 = *(const float4*)(ds + d0 + tx * 4);
#pragma unroll
    for (int i = 0; i < 4; i++) {
      int r = ty + 16 * i;
      float4 v = *(const float4*)(iB + (size_t)(q0 + r) * D_ + d0 + tx * 4);
      ushort4 h;
      h.x = f2bf(v.x * s4.x); h.y = f2bf(v.y * s4.y);
      h.z = f2bf(v.z * s4.z); h.w = f2bf(v.w * s4.w);
      *(ushort4*)(qB + (size_t)(q0 + r) * D_ + d0 + tx * 4) = h;
    }
  }
}

// ---------------------------------------------------------------------------
// gemm_bt: C[M,N] = A[M,K] * B[N,K]^T per batch.
// Geometry: 256x256 tile, BK=64, 8 waves (2M x 4N), wave tile 128x64,
//   acc[8][4] 16x16x32 frags. LDS per matrix [2 buf][256 rows][64 k] bf16
//   (32 KiB/buf), XOR chunk swizzle: 16B chunk (row, s) stored at
//   s' = s ^ (row&7); applied to global SOURCE of global_load_lds (dest
//   linear) and to the ds_read address (rule 21). 8 lanes per 16B
//   bank-group on every wave64 b128 read -> conflict-free.
// SCHEDULE v4 (read-ahead pipeline — LDS drain overlaps MFMA):
//   4 phases/tile; quadrant q(mh,nh) order q00,q01,q11,q10. Phase:
//     { stage 1 granule of tile t+1; counted vmcnt; s_barrier;
//       lgkmcnt(0)  <- drains PREVIOUS phase's ds_reads = this MFMA's frags;
//       issue NEXT phase's ds_reads (execute under this MFMA cluster);
//       sched_barrier; setprio(1); 16 MFMA; setprio(0) }
//   Named frag banks (no runtime indexing, rule #20): afA (A-half0),
//   afB (A-half1), BI/BO (B-halves, role-swap per tile -> t-loop unrolled x2).
//   Per-phase WAR check: p0 MFMA(afA,BI) reads->BO; p1 MFMA(afA,BO)
//   reads->afB; p2 MFMA(afB,BO) no reads; p3 MFMA(afB,BI) reads->afA,BO. OK.
//   Staging granules = the interleaved row-sets the waves actually read:
//     A granule g: rows g*64 + [0,64) u (128 + g*64 + [0,64))
//     B granule g: rows g*32 + {0,64,128,192} + [0,32)
//   so "granule resident" == "phase's reads resident". No wave-instruction
//   straddles a granule discontinuity (boundaries at c%256==0).
//   vmcnt/tile (1 stage = 2 loads/thread): p0: W4 (completes B-beta(t)),
//   p1: W4 (A-beta(t)), p2: none, p3: W4 (A-alpha,B-alpha(t+1)).
//   Invariant: 4 loads in flight at tile entry; never 0 mid-loop.
//   Last tile: p0 W2, p1 W0 (also drains all loads before endpgm), p3 skip.
//   Clobber safety: skew < 1 phase (1 barrier/phase); every stage-write is
//   buffer-disjoint from any possibly-pending ds_read (checked per phase).
// MODE 1: score GEMM; E=exp(s) bf16 (masked->0) + atomic denom row sums.
// MODE 0: out GEMM; divides by denom[row], stores f32.
// MODE 2: fallback (in-loop rowsum from A banks).
// ---------------------------------------------------------------------------
template <int MODE>
__global__ __launch_bounds__(512, 2) void gemm_bt(
    const u16* __restrict__ A, const u16* __restrict__ Bm,
    void* __restrict__ C, const float* __restrict__ mask,
    float* __restrict__ denom, int K, int ld, int ldc,
    size_t sA, size_t sB, size_t sC) {
  __shared__ __align__(16) u16 As[2 * 16384];   // [buf][256][64]
  __shared__ __align__(16) u16 Bs[2 * 16384];

  const int tid = threadIdx.x;
  const int lane = tid & 63, w = tid >> 6;
  const int lm = lane & 15, quad = (lane >> 4) & 3;
  const int wm = (w >> 2) * 128, wn = (w & 3) * 64;

  // ---- swizzle: batch = bid&7 (XCD affinity), GM=4 m-groups, n-fast ----
  const int tiles_n = gridDim.x;
  int bid = (blockIdx.z * gridDim.y + blockIdx.y) * tiles_n + blockIdx.x;
  int bz = bid & 7;
  int s = bid >> 3;
  const int GM = 4;
  int per_group = GM * tiles_n;
  int group = s / per_group;
  int rem = s - group * per_group;
  int tm = group * GM + (rem & (GM - 1));
  int tn = rem >> 2;

  const u16* Ab = A  + (size_t)bz * sA + (size_t)(tm * 256) * ld;
  const u16* Bb = Bm + (size_t)bz * sB + (size_t)(tn * 256) * ld;

  // ---- staging precompute: thread covers chunks c = tid, tid+512 of a
  // 1024-chunk granule. rho=c>>3 local row idx, sl=c&7 LDS slot.
  // LDS linear (chunk c at row(rho)*8 + sl); global source pre-swizzled.
  int goffA[2], ldsA[2], goffB[2], ldsB[2];
#pragma unroll
  for (int j = 0; j < 2; j++) {
    int c = tid + 512 * j;
    int rho = c >> 3, sl = c & 7;
    int rA = (rho & 63) + ((rho >> 6) << 7);   // rows [0,64) u [128,192)
    int rB = (rho & 31) + ((rho >> 5) << 6);   // rows {0,64,128,192}+[0,32)
    int gsl = (sl ^ (rho & 7)) * 8;            // swizzled global k-chunk
    goffA[j] = rA * ld + gsl;
    ldsA[j]  = rA * 64 + sl * 8;
    goffB[j] = rB * ld + gsl;
    ldsB[j]  = rB * 64 + sl * 8;
  }

  auto stA = [&](int g, int buf, int k0) {
#pragma unroll
    for (int j = 0; j < 2; j++)
      __builtin_amdgcn_global_load_lds(
          (GAS void*)(Ab + (size_t)g * 64 * ld + goffA[j] + k0),
          (LAS void*)(As + buf * 16384 + g * 4096 + ldsA[j]), 16, 0, 0);
  };
  auto stB = [&](int g, int buf, int k0) {
#pragma unroll
    for (int j = 0; j < 2; j++)
      __builtin_amdgcn_global_load_lds(
          (GAS void*)(Bb + (size_t)g * 32 * ld + goffB[j] + k0),
          (LAS void*)(Bs + buf * 16384 + g * 2048 + ldsB[j]), 16, 0, 0);
  };

  // ---- fragment-read addressing: logical k-chunk (ks*4+quad) at row
  // (base16+lm): swizzled slot = chunk ^ (lm&7) (row&7 == lm&7).
  const int ka0 = ((0 + quad) ^ (lm & 7)) * 8;
  const int ka1 = ((4 + quad) ^ (lm & 7)) * 8;

  short8 afA[8], afB[8], bfP[4], bfQ[4];   // named banks (static indexing)
  floatx4 acc[8][4];
#pragma unroll
  for (int i = 0; i < 8; i++)
#pragma unroll
    for (int j = 0; j < 4; j++)
      acc[i][j] = {0.f, 0.f, 0.f, 0.f};
  float rs[8] = {0.f, 0.f, 0.f, 0.f, 0.f, 0.f, 0.f, 0.f};

#define VW(N) { asm volatile("s_waitcnt vmcnt(" #N ")" ::: "memory"); \
                __builtin_amdgcn_sched_barrier(0); }

#define RD_A(BANK, MH, BB)                                                    \
  { _Pragma("unroll")                                                         \
    for (int m = 0; m < 4; m++) {                                             \
      BANK[m*2+0] = *(const short8*)(As + (BB)*16384 +                        \
          ((wm + (MH)*64 + m*16 + lm) << 6) + ka0);                           \
      BANK[m*2+1] = *(const short8*)(As + (BB)*16384 +                        \
          ((wm + (MH)*64 + m*16 + lm) << 6) + ka1);                           \
    } }
#define RD_B(BANK, NH, BB)                                                    \
  { _Pragma("unroll")                                                         \
    for (int n = 0; n < 2; n++) {                                             \
      BANK[n*2+0] = *(const short8*)(Bs + (BB)*16384 +                        \
          ((wn + (NH)*32 + n*16 + lm) << 6) + ka0);                           \
      BANK[n*2+1] = *(const short8*)(Bs + (BB)*16384 +                        \
          ((wn + (NH)*32 + n*16 + lm) << 6) + ka1);                           \
    } }
#define SUMA(BANK, O)                                                         \
  if constexpr (MODE == 2) {                                                  \
    _Pragma("unroll")                                                         \
    for (int m = 0; m < 8; m++) {                                             \
      uint4 u = *(const uint4*)&BANK[m];                                      \
      rs[(O) + (m >> 1)] +=                                                   \
          __uint_as_float(u.x << 16) + __uint_as_float(u.x & 0xffff0000u)     \
        + __uint_as_float(u.y << 16) + __uint_as_float(u.y & 0xffff0000u)     \
        + __uint_as_float(u.z << 16) + __uint_as_float(u.z & 0xffff0000u)     \
        + __uint_as_float(u.w << 16) + __uint_as_float(u.w & 0xffff0000u);    \
    } }

// Phase: stage -> counted vmcnt -> barrier -> lgkm0 (prev reads = this
// MFMA's frags) -> issue NEXT phase's reads -> MFMA cluster (16).
#define PH(STG, WAITS, SUMS, READS, MH, NH, ABANK, BBANK)                     \
  {                                                                           \
    __builtin_amdgcn_sched_barrier(0);                                        \
    STG;                                                                      \
    WAITS;                                                                    \
    __builtin_amdgcn_s_barrier();                                             \
    asm volatile("s_waitcnt lgkmcnt(0)" ::: "memory");                        \
    __builtin_amdgcn_sched_barrier(0);                                        \
    SUMS;                                                                     \
    READS;                                                                    \
    __builtin_amdgcn_sched_barrier(0);                                        \
    __builtin_amdgcn_s_setprio(1);                                            \
    _Pragma("unroll")                                                         \
    for (int m = 0; m < 4; m++)                                               \
      _Pragma("unroll")                                                       \
      for (int n = 0; n < 2; n++)                                             \
        _Pragma("unroll")                                                     \
        for (int ks = 0; ks < 2; ks++)                                        \
          acc[(MH)*4+m][(NH)*2+n] = __builtin_amdgcn_mfma_f32_16x16x32_bf16(  \
              ABANK[m*2+ks], BBANK[n*2+ks], acc[(MH)*4+m][(NH)*2+n], 0,0,0);  \
    __builtin_amdgcn_s_setprio(0);                                            \
    __builtin_amdgcn_sched_barrier(0);                                        \
  }

// One K-tile. CUR/NB = buffers, BI/BO = B-frag banks (role-swap per tile),
// HAVE = tile t+1 exists, KN = t+1 k-offset.
#define TILE(CUR, NB, BI, BO, HAVE, KN)                                       \
  PH(if (HAVE) stA(0, NB, KN),                                                \
     if (HAVE) { VW(4) } else { VW(2) },                                      \
     SUMA(afA, 0),                                                            \
     RD_B(BO, 1, CUR),                                                        \
     0, 0, afA, BI)                                                           \
  PH(if (HAVE) stB(0, NB, KN),                                                \
     if (HAVE) { VW(4) } else { VW(0) },                                      \
     {},                                                                      \
     RD_A(afB, 1, CUR),                                                       \
     0, 1, afA, BO)                                                           \
  PH(if (HAVE) stB(1, NB, KN), {}, SUMA(afB, 4), {}, 1, 1, afB, BO)           \
  PH(if (HAVE) stA(1, NB, KN),                                                \
     if (HAVE) { VW(4) },                                                     \
     {},                                                                      \
     if (HAVE) { RD_A(afA, 0, NB) RD_B(BO, 0, NB) },                          \
     1, 0, afB, BI)

  const int NT = K >> 6;
  // prologue: stage tile0 granules in steady order (Aa, Ba, Bb, Ab);
  // vmcnt(4) -> Aa,Ba resident (Bb,Ab in flight = steady invariant);
  // barrier collectivizes; then issue tile0's first-phase frags.
  stA(0, 0, 0); stB(0, 0, 0); stB(1, 0, 0); stA(1, 0, 0);
  VW(4);
  __builtin_amdgcn_s_barrier();
  RD_A(afA, 0, 0)
  RD_B(bfP, 0, 0)

  for (int tt = 0; tt < NT; tt += 2) {
    TILE(0, 1, bfP, bfQ, true, (tt + 1) << 6)
    TILE(1, 0, bfQ, bfP, (tt + 2 < NT), (tt + 2) << 6)
  }
#undef TILE
#undef PH
#undef RD_A
#undef RD_B
#undef SUMA
#undef VW

  // C/D layout: col = lane&15, row = quad*4 + reg  [measured m89/m91]
  const int gm0 = tm * 256 + wm + quad * 4;
  const int gn0 = tn * 256 + wn + lm;
  const size_t cb = (size_t)bz * sC;

  if constexpr (MODE == 1) {
    const float* mrow = mask + (size_t)bz * LK_;
    bool msk[4];
#pragma unroll
    for (int ni = 0; ni < 4; ni++) msk[ni] = (mrow[gn0 + ni * 16] != 0.0f);
#pragma unroll
    for (int mi = 0; mi < 8; mi++) {
#pragma unroll
      for (int r = 0; r < 4; r++) {
        int row = gm0 + mi * 16 + r;
        size_t rowoff = cb + (size_t)row * ldc + gn0;
        float part = 0.f;
#pragma unroll
        for (int ni = 0; ni < 4; ni++) {
          float e = msk[ni] ? 0.f : __expf(acc[mi][ni][r]);
          u16 h = f2bf(e);
          ((u16*)C)[rowoff + ni * 16] = h;
          part += bf2f(h);   // sum the rounded value GEMM2 will actually use
        }
        if (denom) {
          part += __shfl_xor(part, 1, 64);
          part += __shfl_xor(part, 2, 64);
          part += __shfl_xor(part, 4, 64);
          part += __shfl_xor(part, 8, 64);
          if (lm == 0) atomicAdd(&denom[(size_t)bz * LQ_ + row], part);
        }
      }
    }
  } else if constexpr (MODE == 0) {
#pragma unroll
    for (int mi = 0; mi < 8; mi++) {
#pragma unroll
      for (int r = 0; r < 4; r++) {
        int row = gm0 + mi * 16 + r;
        float is = 1.0f / denom[(size_t)bz * LQ_ + row];
        size_t rowoff = cb + (size_t)row * ldc + gn0;
#pragma unroll
        for (int ni = 0; ni < 4; ni++)
          ((float*)C)[rowoff + ni * 16] = acc[mi][ni][r] * is;
      }
    }
  } else {  // MODE 2 fallback: finish in-loop rowsum
    float inv[8];
#pragma unroll
    for (int mi = 0; mi < 8; mi++) {
      rs[mi] += __shfl_xor(rs[mi], 16, 64);
      rs[mi] += __shfl_xor(rs[mi], 32, 64);
      inv[mi] = 1.0f / rs[mi];
    }
#pragma unroll
    for (int mi = 0; mi < 8; mi++) {
#pragma unroll
      for (int r = 0; r < 4; r++) {
        size_t rowoff = cb + (size_t)(gm0 + mi * 16 + r) * ldc + gn0;
        float is = __shfl(inv[mi], quad * 4 + r, 64);
#pragma unroll
        for (int ni = 0; ni < 4; ni++)
          ((float*)C)[rowoff + ni * 16] = acc[mi][ni][r] * is;
      }
    }
  }
}

// ---------------------------------------------------------------------------
// kernel_launch
// Inputs: 0=input [B,LQ,D] f32, 1=memory [B,LK,D] f32, 2=mask [B,LK] f32,
//         3=w_input [1,D] f32 (UNUSED: softmax is shift-invariant along k),
//         4=dot_scale [D] f32.
// Workspace layout (160 MB + 64 KB):
//   qb bf16 [B,LQ,D] @0 | mb bf16 [B,LK,D] @32MB | mbT bf16 [B,D,LK] @64MB
//   E bf16 [B,LQ,LK] @96MB | denom f32 [B,LQ] @160MB (if ws permits)
// ---------------------------------------------------------------------------
extern "C" void kernel_launch(void* const* d_in, const int* in_sizes, int n_in,
                              void* d_out, int out_size, void* d_ws, size_t ws_size,
                              hipStream_t stream) {
  const float* input  = (const float*)d_in[0];
  const float* memory = (const float*)d_in[1];
  const float* mask   = (const float*)d_in[2];
  const float* dscale = (const float*)d_in[4];

  char* ws = (char*)d_ws;
  u16* qb  = (u16*)(ws);
  u16* mb  = (u16*)(ws + (size_t)32 * 1024 * 1024);
  u16* mbT = (u16*)(ws + (size_t)64 * 1024 * 1024);
  u16* E   = (u16*)(ws + (size_t)96 * 1024 * 1024);
  size_t base = (size_t)160 * 1024 * 1024;
  bool have_denom = ws_size >= base + (size_t)B_ * LQ_ * sizeof(float);
  float* denom = have_denom ? (float*)(ws + base) : nullptr;
  float* out = (float*)d_out;

  hipLaunchKernelGGL(prep, dim3(32, 32, B_), dim3(256), 0, stream,
                     input, memory, dscale, qb, mb, mbT, denom);
  // E = exp(qb * mb^T), masked -> 0 : M=LQ, N=LK, K=D (+ denom accumulation)
  hipLaunchKernelGGL((gemm_bt<1>), dim3(LK_ / 256, LQ_ / 256, B_), dim3(512), 0,
                     stream, qb, mb, (void*)E, mask, denom, D_, D_, LK_,
                     (size_t)LQ_ * D_, (size_t)LK_ * D_, (size_t)LQ_ * LK_);
  // out = (E * mbT^T) / denom : M=LQ, N=D, K=LK
  if (have_denom)
    hipLaunchKernelGGL((gemm_bt<0>), dim3(D_ / 256, LQ_ / 256, B_), dim3(512), 0,
                       stream, E, mbT, (void*)out, nullptr, denom, LK_, LK_, D_,
                       (size_t)LQ_ * LK_, (size_t)D_ * LK_, (size_t)LQ_ * D_);
  else
    hipLaunchKernelGGL((gemm_bt<2>), dim3(D_ / 256, LQ_ / 256, B_), dim3(512), 0,
                       stream, E, mbT, (void*)out, nullptr, nullptr, LK_, LK_, D_,
                       (size_t)LQ_ * LK_, (size_t)D_ * LK_, (size_t)LQ_ * D_);
}

// Round 5
// 314.067 us; speedup vs baseline: 1.1772x; 1.1772x over previous
//
#include <hip/hip_runtime.h>

// Problem constants (B, LQ, LK, D from the reference)
#define B_  8
#define LQ_ 2048
#define LK_ 2048
#define D_  1024

typedef unsigned short u16;
using short8  = __attribute__((ext_vector_type(8))) short;   // 8 bf16 = 4 VGPRs (MFMA A/B frag)
using floatx4 = __attribute__((ext_vector_type(4))) float;   // MFMA C/D frag

#define GAS __attribute__((address_space(1)))
#define LAS __attribute__((address_space(3)))

__device__ __forceinline__ u16 f2bf(float f) {
  unsigned u = __float_as_uint(f);
  u += 0x7fffu + ((u >> 16) & 1u);   // round-to-nearest-even
  return (u16)(u >> 16);
}
__device__ __forceinline__ float bf2f(u16 h) {
  return __uint_as_float(((unsigned)h) << 16);
}

// ---------------------------------------------------------------------------
// prep (unchanged)
// ---------------------------------------------------------------------------
__global__ void prep(const float* __restrict__ in, const float* __restrict__ mem,
                     const float* __restrict__ ds, u16* __restrict__ qb,
                     u16* __restrict__ mb, u16* __restrict__ mbT,
                     float* __restrict__ denom) {
  __shared__ u16 tile[64][68];
  int tid = threadIdx.x;
  int tx = tid & 15, ty = tid >> 4;
  int b = blockIdx.z;

  if (denom && blockIdx.y == 16 && blockIdx.x == 0 && blockIdx.z == 0) {
    float4 z = {0.f, 0.f, 0.f, 0.f};
    float4* d4 = (float4*)denom;
#pragma unroll
    for (int i = 0; i < (B_ * LQ_ / 4) / 256; i++)
      d4[tid + i * 256] = z;
  }

  if (blockIdx.y < 16) {
    int k0 = blockIdx.x * 64, d0 = blockIdx.y * 64;
    const float* mB = mem + (size_t)b * LK_ * D_;
    u16* mbB = mb  + (size_t)b * LK_ * D_;
    u16* mtB = mbT + (size_t)b * D_ * LK_;
#pragma unroll
    for (int i = 0; i < 4; i++) {
      int r = ty + 16 * i;
      float4 v = *(const float4*)(mB + (size_t)(k0 + r) * D_ + d0 + tx * 4);
      ushort4 h;
      h.x = f2bf(v.x); h.y = f2bf(v.y); h.z = f2bf(v.z); h.w = f2bf(v.w);
      *(ushort4*)(mbB + (size_t)(k0 + r) * D_ + d0 + tx * 4) = h;
      *(ushort4*)(&tile[r][tx * 4]) = h;
    }
    __syncthreads();
#pragma unroll
    for (int i = 0; i < 4; i++) {
      int rr = ty + 16 * i;
      ushort4 o;
      o.x = tile[tx * 4 + 0][rr];
      o.y = tile[tx * 4 + 1][rr];
      o.z = tile[tx * 4 + 2][rr];
      o.w = tile[tx * 4 + 3][rr];
      *(ushort4*)(mtB + (size_t)(d0 + rr) * LK_ + k0 + tx * 4) = o;
    }
  } else {
    int q0 = blockIdx.x * 64, d0 = (blockIdx.y - 16) * 64;
    const float* iB = in + (size_t)b * LQ_ * D_;
    u16* qB = qb + (size_t)b * LQ_ * D_;
    float4 s4 = *(const float4*)(ds + d0 + tx * 4);
#pragma unroll
    for (int i = 0; i < 4; i++) {
      int r = ty + 16 * i;
      float4 v = *(const float4*)(iB + (size_t)(q0 + r) * D_ + d0 + tx * 4);
      ushort4 h;
      h.x = f2bf(v.x * s4.x); h.y = f2bf(v.y * s4.y);
      h.z = f2bf(v.z * s4.z); h.w = f2bf(v.w * s4.w);
      *(ushort4*)(qB + (size_t)(q0 + r) * D_ + d0 + tx * 4) = h;
    }
  }
}

// ---------------------------------------------------------------------------
// gemm_bt: C[M,N] = A[M,K] * B[N,K]^T per batch.
// Geometry: 256x256 tile, BK=64, 8 waves (2M x 4N), wave tile 128x64,
//   acc[8][4] 16x16x32 frags (in AGPRs). LDS per matrix [2 buf][256 r][64 k]
//   bf16 = 32 KiB/buf (128 KiB total). XOR swizzle: 16B chunk (row, sl)
//   holds global k-chunk sl^(row&7); applied to the global SOURCE of
//   global_load_lds (LDS dest linear) and to the ds_read address (rule 21).
//   Proven 0-bank-conflict (rounds 1-4).
// SCHEDULE v5 (1 barrier/tile + counted-lgkm in-tile pipeline):
//   Register budget law (round-4 lesson): 2 waves/SIMD = 256 regs TOTAL,
//   acc=128 AGPR -> arch-VGPR must stay <= ~128. Frag banks here:
//   bf[8] (whole-tile B frags, read once) + afE[4]/afO[4] (double-banked
//   A m-pairs) = 16 short8 = 64 VGPR.
//   Per tile (per wave):
//     barrier (cur planes resident, staged last tile, vmcnt(0)-drained)
//     issue bf[8] + afE<-m01 + afO<-m23 (16 ds_reads)
//     issue all 8 stages of tile t+1 -> nb planes (vm queue)
//     lgkm(4)  -> bf+afE done;  MFMA P0 (m01, 16)   | issue afE<-m45
//     lgkm(4)  -> afO done;     MFMA P1 (m23, 16)   | issue afO<-m67
//     lgkm(4)  -> afE done;     MFMA P2 (m45, 16)
//     lgkm(0)  -> afO done;     MFMA P3 (m67, 16)
//     vmcnt(0); barrier
//   Each 4-read burst (~380cy CU-wide) hides under a 620cy MFMA cluster;
//   stages have the whole tile (~2500cy >> 900cy HBM) to land, so the
//   boundary vmcnt(0) is a cheap drain. No intra-tile barriers -> the two
//   waves/SIMD desync via LDS queue order -> cross-wave MFMA/LDS overlap
//   (the regime where setprio pays, T5).
//   SAFETY: reads only touch cur planes, stages only nb; one barrier/tile
//   bounds skew < 1 tile; all reads lgkm(0)-drained before the boundary,
//   so a leader's tile-t+2 stage (into cur_t) can never race a straggler's
//   tile-t read. vmcnt(0) before the barrier makes staged data collective.
// MODE 1: score GEMM; E=exp(s) bf16 (masked->0) + atomic denom row sums.
// MODE 0: out GEMM; divides by denom[row], stores f32.
// MODE 2: fallback (in-loop rowsum from A banks).
// ---------------------------------------------------------------------------
template <int MODE>
__global__ __launch_bounds__(512, 2) void gemm_bt(
    const u16* __restrict__ A, const u16* __restrict__ Bm,
    void* __restrict__ C, const float* __restrict__ mask,
    float* __restrict__ denom, int K, int ld, int ldc,
    size_t sA, size_t sB, size_t sC) {
  __shared__ __align__(16) u16 As[2 * 16384];   // [buf][256][64] u16, 64 KiB
  __shared__ __align__(16) u16 Bs[2 * 16384];

  const int tid = threadIdx.x;
  const int lane = tid & 63, w = tid >> 6;
  const int lm = lane & 15, quad = (lane >> 4) & 3;
  const int wm = (w >> 2) * 128, wn = (w & 3) * 64;

  // ---- swizzle: batch = bid&7 (XCD affinity), GM=4 m-groups, n-fast ----
  const int tiles_n = gridDim.x;
  int bid = (blockIdx.z * gridDim.y + blockIdx.y) * tiles_n + blockIdx.x;
  int bz = bid & 7;
  int s = bid >> 3;
  const int GM = 4;
  int per_group = GM * tiles_n;
  int group = s / per_group;
  int rem = s - group * per_group;
  int tm = group * GM + (rem & (GM - 1));
  int tn = rem >> 2;

  const u16* Ab = A  + (size_t)bz * sA + (size_t)(tm * 256) * ld;
  const u16* Bb = Bm + (size_t)bz * sB + (size_t)(tn * 256) * ld;

  // ---- staging: 2048 chunks of 16 B per matrix per tile; thread covers
  // c = tid + 512j, j=0..3. rho = c>>3 (row), sl = c&7 (LDS slot).
  // LDS dest linear (chunk c at byte c*16 = wave-uniform base + lane*16);
  // global source pre-swizzled: k-chunk = sl ^ (rho&7).
  int goff[4], lofs[4];
#pragma unroll
  for (int j = 0; j < 4; j++) {
    int c = tid + 512 * j;
    int rho = c >> 3, sl = c & 7;
    goff[j] = rho * ld + (sl ^ (rho & 7)) * 8;   // elements
    lofs[j] = c * 8;                              // elements
  }

  auto stage = [&](int buf, int k0) {
#pragma unroll
    for (int j = 0; j < 4; j++)
      __builtin_amdgcn_global_load_lds((GAS void*)(Ab + goff[j] + k0),
                                       (LAS void*)(As + buf * 16384 + lofs[j]),
                                       16, 0, 0);
#pragma unroll
    for (int j = 0; j < 4; j++)
      __builtin_amdgcn_global_load_lds((GAS void*)(Bb + goff[j] + k0),
                                       (LAS void*)(Bs + buf * 16384 + lofs[j]),
                                       16, 0, 0);
  };

  // ---- fragment reads: logical k-chunk (ks*4+quad) at row (base16+lm),
  // swizzled slot = chunk ^ (lm&7) (row&7 == lm&7). Element offsets:
  const int ka0 = (((0 + quad)) ^ (lm & 7)) * 8;
  const int ka1 = (((4 + quad)) ^ (lm & 7)) * 8;

  short8 bf[8], afE[4], afO[4];   // 16 short8 = 64 VGPR
  floatx4 acc[8][4];
#pragma unroll
  for (int i = 0; i < 8; i++)
#pragma unroll
    for (int j = 0; j < 4; j++)
      acc[i][j] = {0.f, 0.f, 0.f, 0.f};
  float rs[8] = {0.f, 0.f, 0.f, 0.f, 0.f, 0.f, 0.f, 0.f};   // MODE 2 only

#define SB __builtin_amdgcn_sched_barrier(0)
#define LG(N) { asm volatile("s_waitcnt lgkmcnt(" #N ")" ::: "memory"); SB; }
#define VM0   { asm volatile("s_waitcnt vmcnt(0)" ::: "memory"); SB; }

#define RD_BF(CO)                                                             \
  { _Pragma("unroll")                                                         \
    for (int n = 0; n < 4; n++) {                                             \
      bf[n * 2 + 0] = *(const short8*)(Bs + (CO) + ((wn + n * 16 + lm) << 6) + ka0); \
      bf[n * 2 + 1] = *(const short8*)(Bs + (CO) + ((wn + n * 16 + lm) << 6) + ka1); \
    } }
#define RD_AF(BANK, MP, CO)                                                   \
  { _Pragma("unroll")                                                         \
    for (int mi = 0; mi < 2; mi++) {                                          \
      BANK[mi * 2 + 0] = *(const short8*)(As + (CO) + ((wm + (MP) * 32 + mi * 16 + lm) << 6) + ka0); \
      BANK[mi * 2 + 1] = *(const short8*)(As + (CO) + ((wm + (MP) * 32 + mi * 16 + lm) << 6) + ka1); \
    } }
#define SUMS(BANK, P)                                                         \
  if constexpr (MODE == 2) {                                                  \
    _Pragma("unroll")                                                         \
    for (int mi = 0; mi < 2; mi++)                                            \
      _Pragma("unroll")                                                       \
      for (int ks = 0; ks < 2; ks++) {                                        \
        uint4 u = *(const uint4*)&BANK[mi * 2 + ks];                          \
        rs[(P) * 2 + mi] +=                                                   \
            __uint_as_float(u.x << 16) + __uint_as_float(u.x & 0xffff0000u)   \
          + __uint_as_float(u.y << 16) + __uint_as_float(u.y & 0xffff0000u)   \
          + __uint_as_float(u.z << 16) + __uint_as_float(u.z & 0xffff0000u)   \
          + __uint_as_float(u.w << 16) + __uint_as_float(u.w & 0xffff0000u);  \
      } }
#define MM(P, BANK)                                                           \
  { __builtin_amdgcn_s_setprio(1);                                            \
    _Pragma("unroll")                                                         \
    for (int mi = 0; mi < 2; mi++)                                            \
      _Pragma("unroll")                                                       \
      for (int n = 0; n < 4; n++)                                             \
        _Pragma("unroll")                                                     \
        for (int ks = 0; ks < 2; ks++)                                        \
          acc[(P) * 2 + mi][n] = __builtin_amdgcn_mfma_f32_16x16x32_bf16(     \
              BANK[mi * 2 + ks], bf[n * 2 + ks], acc[(P) * 2 + mi][n], 0, 0, 0); \
    __builtin_amdgcn_s_setprio(0); }

  const int NT = K >> 6;
  // prologue: stage tile 0 into buf 0; drain; collectivize.
  stage(0, 0);
  VM0;
  __builtin_amdgcn_s_barrier();

  for (int t = 0; t < NT; ++t) {
    const int co = (t & 1) * 16384;
    const int nbuf = (t & 1) ^ 1;
    const bool have = (t + 1 < NT);
    const int kn = (t + 1) << 6;

    SB;
    RD_BF(co) RD_AF(afE, 0, co) RD_AF(afO, 1, co) SB;        // 16 ds_reads
    if (have) stage(nbuf, kn);                                // 8 vm loads
    SB;
    LG(4)  SUMS(afE, 0) MM(0, afE) SB;                        // bf+afE ready
    RD_AF(afE, 2, co) SB;
    LG(4)  SUMS(afO, 1) MM(1, afO) SB;                        // afO(m23) ready
    RD_AF(afO, 3, co) SB;
    LG(4)  SUMS(afE, 2) MM(2, afE) SB;                        // afE(m45) ready
    LG(0)  SUMS(afO, 3) MM(3, afO) SB;                        // afO(m67) ready
    VM0;                                                      // t+1 resident
    __builtin_amdgcn_s_barrier();
  }
#undef MM
#undef SUMS
#undef RD_AF
#undef RD_BF
#undef LG
#undef VM0
#undef SB

  // C/D layout: col = lane&15, row = quad*4 + reg  [measured m89/m91]
  const int gm0 = tm * 256 + wm + quad * 4;
  const int gn0 = tn * 256 + wn + lm;
  const size_t cb = (size_t)bz * sC;

  if constexpr (MODE == 1) {
    const float* mrow = mask + (size_t)bz * LK_;
    bool msk[4];
#pragma unroll
    for (int ni = 0; ni < 4; ni++) msk[ni] = (mrow[gn0 + ni * 16] != 0.0f);
#pragma unroll
    for (int mi = 0; mi < 8; mi++) {
#pragma unroll
      for (int r = 0; r < 4; r++) {
        int row = gm0 + mi * 16 + r;
        size_t rowoff = cb + (size_t)row * ldc + gn0;
        float part = 0.f;
#pragma unroll
        for (int ni = 0; ni < 4; ni++) {
          float e = msk[ni] ? 0.f : __expf(acc[mi][ni][r]);
          u16 h = f2bf(e);
          ((u16*)C)[rowoff + ni * 16] = h;
          part += bf2f(h);   // sum the rounded value GEMM2 will actually use
        }
        if (denom) {
          part += __shfl_xor(part, 1, 64);
          part += __shfl_xor(part, 2, 64);
          part += __shfl_xor(part, 4, 64);
          part += __shfl_xor(part, 8, 64);
          if (lm == 0) atomicAdd(&denom[(size_t)bz * LQ_ + row], part);
        }
      }
    }
  } else if constexpr (MODE == 0) {
#pragma unroll
    for (int mi = 0; mi < 8; mi++) {
#pragma unroll
      for (int r = 0; r < 4; r++) {
        int row = gm0 + mi * 16 + r;
        float is = 1.0f / denom[(size_t)bz * LQ_ + row];
        size_t rowoff = cb + (size_t)row * ldc + gn0;
#pragma unroll
        for (int ni = 0; ni < 4; ni++)
          ((float*)C)[rowoff + ni * 16] = acc[mi][ni][r] * is;
      }
    }
  } else {  // MODE 2 fallback: finish in-loop rowsum
    float inv[8];
#pragma unroll
    for (int mi = 0; mi < 8; mi++) {
      rs[mi] += __shfl_xor(rs[mi], 16, 64);
      rs[mi] += __shfl_xor(rs[mi], 32, 64);
      inv[mi] = 1.0f / rs[mi];
    }
#pragma unroll
    for (int mi = 0; mi < 8; mi++) {
#pragma unroll
      for (int r = 0; r < 4; r++) {
        size_t rowoff = cb + (size_t)(gm0 + mi * 16 + r) * ldc + gn0;
        float is = __shfl(inv[mi], quad * 4 + r, 64);
#pragma unroll
        for (int ni = 0; ni < 4; ni++)
          ((float*)C)[rowoff + ni * 16] = acc[mi][ni][r] * is;
      }
    }
  }
}

// ---------------------------------------------------------------------------
// kernel_launch
// Inputs: 0=input [B,LQ,D] f32, 1=memory [B,LK,D] f32, 2=mask [B,LK] f32,
//         3=w_input [1,D] f32 (UNUSED: softmax is shift-invariant along k),
//         4=dot_scale [D] f32.
// Workspace layout (160 MB + 64 KB):
//   qb bf16 [B,LQ,D] @0 | mb bf16 [B,LK,D] @32MB | mbT bf16 [B,D,LK] @64MB
//   E bf16 [B,LQ,LK] @96MB | denom f32 [B,LQ] @160MB (if ws permits)
// ---------------------------------------------------------------------------
extern "C" void kernel_launch(void* const* d_in, const int* in_sizes, int n_in,
                              void* d_out, int out_size, void* d_ws, size_t ws_size,
                              hipStream_t stream) {
  const float* input  = (const float*)d_in[0];
  const float* memory = (const float*)d_in[1];
  const float* mask   = (const float*)d_in[2];
  const float* dscale = (const float*)d_in[4];

  char* ws = (char*)d_ws;
  u16* qb  = (u16*)(ws);
  u16* mb  = (u16*)(ws + (size_t)32 * 1024 * 1024);
  u16* mbT = (u16*)(ws + (size_t)64 * 1024 * 1024);
  u16* E   = (u16*)(ws + (size_t)96 * 1024 * 1024);
  size_t base = (size_t)160 * 1024 * 1024;
  bool have_denom = ws_size >= base + (size_t)B_ * LQ_ * sizeof(float);
  float* denom = have_denom ? (float*)(ws + base) : nullptr;
  float* out = (float*)d_out;

  hipLaunchKernelGGL(prep, dim3(32, 32, B_), dim3(256), 0, stream,
                     input, memory, dscale, qb, mb, mbT, denom);
  // E = exp(qb * mb^T), masked -> 0 : M=LQ, N=LK, K=D (+ denom accumulation)
  hipLaunchKernelGGL((gemm_bt<1>), dim3(LK_ / 256, LQ_ / 256, B_), dim3(512), 0,
                     stream, qb, mb, (void*)E, mask, denom, D_, D_, LK_,
                     (size_t)LQ_ * D_, (size_t)LK_ * D_, (size_t)LQ_ * LK_);
  // out = (E * mbT^T) / denom : M=LQ, N=D, K=LK
  if (have_denom)
    hipLaunchKernelGGL((gemm_bt<0>), dim3(D_ / 256, LQ_ / 256, B_), dim3(512), 0,
                       stream, E, mbT, (void*)out, nullptr, denom, LK_, LK_, D_,
                       (size_t)LQ_ * LK_, (size_t)D_ * LK_, (size_t)LQ_ * D_);
  else
    hipLaunchKernelGGL((gemm_bt<2>), dim3(D_ / 256, LQ_ / 256, B_), dim3(512), 0,
                       stream, E, mbT, (void*)out, nullptr, nullptr, LK_, LK_, D_,
                       (size_t)LQ_ * LK_, (size_t)D_ * LK_, (size_t)LQ_ * D_);
}